// Round 1
// baseline (327.232 us; speedup 1.0000x reference)
//
#include <hip/hip_runtime.h>
#include <hip/hip_bf16.h>
#include <stdint.h>

// TernaryConv2d: y = conv2d(x, alpha*ternary(W), SAME) + b
// x: (32,56,56,256) NHWC fp32, W: (3,3,256,256) HWIO fp32, b: (256,) fp32
// Implicit GEMM: M=100352, N=256, K=2304. bf16 MFMA, alpha fp32 epilogue.
//
// R1: reduction atomics fixed (670->349).
// R2: XOR-swizzled LDS chunks, kc-outer/tap-inner K-loop, fused sumabs (349->299).
// R3: conv -> 256x256 tile / 512 thr / 8 waves, BK=64, double-buffered LDS,
//     4 quadrant-phases per K-tile, counted vmcnt(8) across barriers (T3+T4),
//     s_setprio around MFMA clusters (T5). Old structure was at the documented
//     ~950TF 2-barrier-drain ceiling (MfmaUtil 42%). Also fixed PAD_BLOCKS
//     13454->13456 (16 halo pixels were never zeroed).
//
// ws layout:
//   [0..511]            : ull scalars {sumAbs_q40, sumBeyond_q40, countBeyond}
//   [512..2360319]      : WqT bf16 [256 co][2304 k]  (k = tap*256 + ci)
//   [2360320..57476095] : xpad bf16 [32][58][58][256] (zero-padded halo)

typedef __attribute__((ext_vector_type(8))) short short8;
typedef __attribute__((ext_vector_type(4))) float floatx4;

#define Q40 1099511627776.0
#define INV_Q40 (1.0 / 1099511627776.0)
#define NW_ELEMS 589824        // 3*3*256*256
#define K_TOTAL 2304
#define WQT_OFF 512
#define XPAD_OFF 2360320
#define RED_BLOCKS 288         // 288*256*8 == NW_ELEMS exactly
#define PAD_BLOCKS 13456       // 32*58*58*256/8 / 256 (FULL coverage)

__device__ __forceinline__ void async16(const void* g, void* l) {
  __builtin_amdgcn_global_load_lds(
      (const __attribute__((address_space(1))) void*)g,
      (__attribute__((address_space(3))) void*)l, 16, 0, 0);
}

__device__ __forceinline__ ushort f2bf(float f) {
  __hip_bfloat16 h = __float2bfloat16(f);
  return *reinterpret_cast<ushort*>(&h);
}

// ---- fused: blocks 0..287 sum|W|; blocks 288.. pad/convert x -> xpad ----
__global__ __launch_bounds__(256) void pad_sumabs_kernel(
    const float* __restrict__ x, ushort* __restrict__ xpad,
    const float* __restrict__ W, unsigned long long* __restrict__ scal) {
  if (blockIdx.x < RED_BLOCKS) {
    __shared__ double sds[4];
    double v = 0.0;
#pragma unroll
    for (int j = 0; j < 8; j++) {
      uint i = (blockIdx.x * 8 + j) * 256 + threadIdx.x;
      v += (double)fabsf(W[i]);
    }
#pragma unroll
    for (int off = 32; off; off >>= 1) v += __shfl_down(v, off);
    if ((threadIdx.x & 63) == 0) sds[threadIdx.x >> 6] = v;
    __syncthreads();
    if (threadIdx.x == 0) {
      double s = sds[0] + sds[1] + sds[2] + sds[3];
      atomicAdd(&scal[0], (unsigned long long)(s * Q40 + 0.5));
    }
    return;
  }
  uint idx = (blockIdx.x - RED_BLOCKS) * 256 + threadIdx.x;  // 1 thread / 8 ch
  uint c8 = idx & 31;
  uint sp = idx >> 5;                          // n*3364 + hh*58 + ww
  uint ww = sp % 58;
  uint t = sp / 58;
  uint hh = t % 58;
  uint n = t / 58;
  ushort* dst = xpad + ((size_t)sp * 256 + c8 * 8);
  if (hh == 0 || hh == 57 || ww == 0 || ww == 57) {
    uint4 z = {0, 0, 0, 0};
    *(uint4*)dst = z;
  } else {
    const float* src = x + (((size_t)(n * 56 + (hh - 1)) * 56 + (ww - 1)) * 256 + c8 * 8);
    float4 f0 = *(const float4*)src;
    float4 f1 = *(const float4*)(src + 4);
    ushort u[8];
    u[0] = f2bf(f0.x); u[1] = f2bf(f0.y); u[2] = f2bf(f0.z); u[3] = f2bf(f0.w);
    u[4] = f2bf(f1.x); u[5] = f2bf(f1.y); u[6] = f2bf(f1.z); u[7] = f2bf(f1.w);
    *(uint4*)dst = *(uint4*)u;
  }
}

// ---- ternarize: WqT[co][k] in {-1,0,+1}; alpha stats, 2 atomics/block ----
__global__ __launch_bounds__(256) void quant_kernel(const float* __restrict__ W,
                                                    ushort* __restrict__ WqT,
                                                    unsigned long long* __restrict__ scal) {
  __shared__ double sds[4];
  __shared__ unsigned long long cds[4];
  double s = (double)scal[0] * INV_Q40;
  float t = (float)(0.7 * (s / (double)NW_ELEMS));
  double v = 0.0;
  unsigned long long cnt = 0;
#pragma unroll
  for (int j = 0; j < 8; j++) {
    uint i = (blockIdx.x * 8 + j) * 256 + threadIdx.x;
    float w = W[i];
    bool pos = (w > t), neg = (w < -t);
    ushort q = pos ? (ushort)0x3F80 : (neg ? (ushort)0xBF80 : (ushort)0);
    uint k = i >> 8, co = i & 255;
    WqT[(size_t)co * K_TOTAL + k] = q;
    if (pos || neg) { v += (double)fabsf(w); cnt++; }
  }
#pragma unroll
  for (int off = 32; off; off >>= 1) {
    v += __shfl_down(v, off);
    cnt += __shfl_down(cnt, off);
  }
  if ((threadIdx.x & 63) == 0) { sds[threadIdx.x >> 6] = v; cds[threadIdx.x >> 6] = cnt; }
  __syncthreads();
  if (threadIdx.x == 0) {
    double sv = sds[0] + sds[1] + sds[2] + sds[3];
    unsigned long long sc = cds[0] + cds[1] + cds[2] + cds[3];
    atomicAdd(&scal[1], (unsigned long long)(sv * Q40 + 0.5));
    atomicAdd(&scal[2], sc);
  }
}

// K-step s (0..35) -> element offsets into xpad row / WqT row.
__device__ __forceinline__ void koff(int s, uint& ao, uint& bo) {
  uint kcq = (uint)s / 9;
  uint tap = (uint)s - kcq * 9;
  uint ky = tap / 3, kx = tap - ky * 3;
  ao = (ky * 58 + kx) * 256 + kcq * 64;
  bo = tap * 256 + kcq * 64;
}

// ---- implicit-GEMM conv v3: 256x256 tile, 8 waves (2Mx4N), BK=64 ----
// LDS rows: 64 ushort = 128 B. Staging thread (rbase,chunk) loads global
// chunk chunk^(row&7) into linear slot chunk (global_load_lds is linear-dest);
// readers fetch slot (kk*4+fq)^(row&7) -> conflict-free (verified: 0 in R2).
//
// Per K-tile (4 phases, quadrants of the wave's 128x64 output):
//   P1: ds_read A-half0(8 b128)+B-half0(4); bar; lgkm0; 16 MFMA; bar
//   P2: ds_read B-half1(4);                 bar; lgkm0; 16 MFMA; bar
//   P3: ds_read A-half1(8);                 bar; lgkm0; 16 MFMA; bar
//       (after this barrier every wave has retired ALL reads of this buffer)
//   P4: stage tile t+2 into this buffer (8 global_load_lds); 16 MFMA;
//       s_waitcnt vmcnt(8)  <- tile t+1 landed, t+2's 8 stay in flight; bar
__global__ __launch_bounds__(512, 2) void conv_kernel(
    const ushort* __restrict__ xpad, const ushort* __restrict__ WqT,
    const unsigned long long* __restrict__ scal, const float* __restrict__ bias,
    float* __restrict__ out) {
  __shared__ __attribute__((aligned(16))) ushort Alds[2][256 * 64];  // 64 KB
  __shared__ __attribute__((aligned(16))) ushort Blds[2][256 * 64];  // 64 KB
  uint tid = threadIdx.x;
  uint bm = blockIdx.x;

  // staging map: 512 thr x 16B = 8KB/round; 4 rounds each for A,B per tile
  uint chunk = tid & 7, rbase = tid >> 3;      // rbase 0..63
  uint ceff = chunk ^ (rbase & 7);             // pre-swizzled global chunk
  const ushort* asrc[4];
  const ushort* bsrc[4];
#pragma unroll
  for (int i = 0; i < 4; i++) {
    uint row = i * 64 + rbase;
    uint gm = bm * 256 + row;
    uint n = gm / 3136;
    uint rem = gm - n * 3136;
    uint h = rem / 56;
    uint w = rem - h * 56;
    asrc[i] = xpad + (((size_t)(n * 58 + h) * 58 + w) * 256 + ceff * 8);
    bsrc[i] = WqT + ((size_t)row * K_TOTAL + ceff * 8);
  }
  uint ldsoff = tid * 16;  // byte offset in 32KB buffer (== row*128+chunk*16)

  floatx4 acc[8][4];
#pragma unroll
  for (int mt = 0; mt < 8; mt++)
#pragma unroll
    for (int nt = 0; nt < 4; nt++) acc[mt][nt] = (floatx4){0.f, 0.f, 0.f, 0.f};

  uint lane = tid & 63, wv = tid >> 6;
  uint wm = wv >> 2, wn = wv & 3;              // 2x4 wave grid, each 128x64
  uint fr = lane & 15, fq = lane >> 4;
  uint swz = fr & 7;
  uint cs0 = (fq ^ swz) * 16;                  // kk=0 swizzled chunk byte
  uint cs1 = ((fq | 4) ^ swz) * 16;            // kk=1
  uint aB = (wm * 128 + fr) * 128;             // wave A-row base (bytes)
  uint bB = (wn * 64 + fr) * 128;              // wave B-row base (bytes)

  short8 af[4][2], b0[2][2], b1[2][2];

#define STAGE_TILE(BUF, AO, BO)                                               \
  do {                                                                        \
    _Pragma("unroll") for (int i = 0; i < 4; i++)                             \
        async16(asrc[i] + (AO), (char*)&Alds[BUF][0] + i * 8192 + ldsoff);    \
    _Pragma("unroll") for (int i = 0; i < 4; i++)                             \
        async16(bsrc[i] + (BO), (char*)&Blds[BUF][0] + i * 8192 + ldsoff);    \
  } while (0)

#define LDS_A(BUF, MH)                                                        \
  do {                                                                        \
    _Pragma("unroll") for (int mt = 0; mt < 4; mt++) {                        \
      const char* p =                                                         \
          (const char*)&Alds[BUF][0] + aB + ((MH)*64 + mt * 16) * 128;        \
      af[mt][0] = *(const short8*)(p + cs0);                                  \
      af[mt][1] = *(const short8*)(p + cs1);                                  \
    }                                                                         \
  } while (0)

#define LDS_B(BUF, NH, BR)                                                    \
  do {                                                                        \
    _Pragma("unroll") for (int nt = 0; nt < 2; nt++) {                        \
      const char* p =                                                         \
          (const char*)&Blds[BUF][0] + bB + ((NH)*32 + nt * 16) * 128;        \
      BR[nt][0] = *(const short8*)(p + cs0);                                  \
      BR[nt][1] = *(const short8*)(p + cs1);                                  \
    }                                                                         \
  } while (0)

#define MM16(MH, NH, BR)                                                      \
  do {                                                                        \
    __builtin_amdgcn_s_setprio(1);                                            \
    _Pragma("unroll") for (int mt = 0; mt < 4; mt++)                          \
        _Pragma("unroll") for (int nt = 0; nt < 2; nt++) {                    \
      acc[(MH)*4 + mt][(NH)*2 + nt] =                                         \
          __builtin_amdgcn_mfma_f32_16x16x32_bf16(                            \
              af[mt][0], BR[nt][0], acc[(MH)*4 + mt][(NH)*2 + nt], 0, 0, 0);  \
      acc[(MH)*4 + mt][(NH)*2 + nt] =                                         \
          __builtin_amdgcn_mfma_f32_16x16x32_bf16(                            \
              af[mt][1], BR[nt][1], acc[(MH)*4 + mt][(NH)*2 + nt], 0, 0, 0);  \
    }                                                                         \
    __builtin_amdgcn_s_setprio(0);                                            \
  } while (0)

#define LGKM0 asm volatile("s_waitcnt lgkmcnt(0)" ::: "memory")
#define VM8 asm volatile("s_waitcnt vmcnt(8)" ::: "memory")
#define VM0 asm volatile("s_waitcnt vmcnt(0)" ::: "memory")
#define BAR __builtin_amdgcn_s_barrier()

#define KTILE(BUF, STAGE_STMT, VM_STMT)                                       \
  do {                                                                        \
    LDS_A(BUF, 0);                                                            \
    LDS_B(BUF, 0, b0);                                                        \
    BAR;                                                                      \
    LGKM0;                                                                    \
    MM16(0, 0, b0);                                                           \
    BAR;                                                                      \
    LDS_B(BUF, 1, b1);                                                        \
    BAR;                                                                      \
    LGKM0;                                                                    \
    MM16(0, 1, b1);                                                           \
    BAR;                                                                      \
    LDS_A(BUF, 1);                                                            \
    BAR;                                                                      \
    LGKM0;                                                                    \
    MM16(1, 1, b1);                                                           \
    BAR;                                                                      \
    asm volatile("" ::: "memory");                                            \
    STAGE_STMT;                                                               \
    MM16(1, 0, b0);                                                           \
    VM_STMT;                                                                  \
    BAR;                                                                      \
  } while (0)

  // prologue: tiles 0,1 staged; tile0 forced landed, tile1's 8 stay in flight
  uint ao0, bo0, ao1, bo1;
  koff(0, ao0, bo0);
  koff(1, ao1, bo1);
  STAGE_TILE(0, ao0, bo0);
  STAGE_TILE(1, ao1, bo1);
  VM8;
  BAR;

#pragma unroll 1
  for (int t = 0; t < 34; t += 2) {
    uint ao2, bo2, ao3, bo3;
    koff(t + 2, ao2, bo2);
    koff(t + 3, ao3, bo3);
    KTILE(0, STAGE_TILE(0, ao2, bo2), VM8);
    KTILE(1, STAGE_TILE(1, ao3, bo3), VM8);
  }
  // tiles 34, 35: nothing left to stage; drain before last buffer read
  KTILE(0, ((void)0), VM0);
  KTILE(1, ((void)0), ((void)0));

  // epilogue: alpha * acc + bias, fp32 store
  // C/D layout (m89/m91): col = lane&15, row = (lane>>4)*4 + reg
  double sb = (double)scal[1] * INV_Q40;
  double cb = (double)scal[2];
  float alpha = (float)(sb / cb);
#pragma unroll
  for (int mt = 0; mt < 8; mt++) {
    uint mrow = bm * 256 + wm * 128 + mt * 16 + fq * 4;
#pragma unroll
    for (int r = 0; r < 4; r++) {
      float* orow = out + (size_t)(mrow + r) * 256;
#pragma unroll
      for (int nt = 0; nt < 4; nt++) {
        uint col = wn * 64 + nt * 16 + fr;
        orow[col] = acc[mt][nt][r] * alpha + bias[col];
      }
    }
  }
}

extern "C" void kernel_launch(void* const* d_in, const int* in_sizes, int n_in,
                              void* d_out, int out_size, void* d_ws, size_t ws_size,
                              hipStream_t stream) {
  const float* x = (const float*)d_in[0];
  const float* W = (const float*)d_in[1];
  const float* b = (const float*)d_in[2];
  float* out = (float*)d_out;

  unsigned long long* scal = (unsigned long long*)d_ws;
  ushort* WqT = (ushort*)((char*)d_ws + WQT_OFF);
  ushort* xpad = (ushort*)((char*)d_ws + XPAD_OFF);

  hipMemsetAsync(d_ws, 0, 512, stream);
  pad_sumabs_kernel<<<RED_BLOCKS + PAD_BLOCKS, 256, 0, stream>>>(x, xpad, W, scal);
  quant_kernel<<<RED_BLOCKS, 256, 0, stream>>>(W, WqT, scal);
  conv_kernel<<<392, 512, 0, stream>>>(xpad, WqT, scal, b, out);
}

// Round 3
// 294.028 us; speedup vs baseline: 1.1129x; 1.1129x over previous
//
#include <hip/hip_runtime.h>
#include <hip/hip_bf16.h>
#include <stdint.h>

// TernaryConv2d: y = conv2d(x, alpha*ternary(W), SAME) + b
// x: (32,56,56,256) NHWC fp32, W: (3,3,256,256) HWIO fp32, b: (256,) fp32
// Implicit GEMM: M=100352, N=256, K=2304. bf16 MFMA, alpha fp32 epilogue.
//
// R1: reduction atomics fixed (670->349).
// R2: XOR-swizzled LDS chunks, kc-outer/tap-inner K-loop, fused sumabs (349->299).
// R3: 256x256/8-phase port REGRESSED (conv 123->153): 392 blocks @ 1 blk/CU =
//     76.6% packing tail; steady-state MfmaUtil unchanged at ~42%. REVERTED.
// R4: conv = R2 structure exactly. Attack the ~175us non-conv side instead:
//     no memset dispatch, no atomics anywhere (per-block partials + redundant
//     sums), quant does one 16B store/thread instead of 8x2B, 3 dispatches.
//     PAD_BLOCKS 13454->13456 fix kept (16 halo pixels were never zeroed).
// R5: resubmit of R4 — previous round died to an infra error (container
//     failed twice, never reached the GPU). Source re-audited: bounds,
//     races, graph-capture rules all clean.
//
// ws layout:
//   [0..2303]           : pr[288] double  — per-block sum|W| partials
//   [2560..4863]        : qv[288] double  — per-block sum|W beyond t| partials
//   [5120..7423]        : qc[288] ull     — per-block count-beyond partials
//   [8192..1187839]     : WqT bf16 [256 co][2304 k]  (k = tap*256 + ci)
//   [1187840..56303615] : xpad bf16 [32][58][58][256] (zero-padded halo)

typedef __attribute__((ext_vector_type(8))) short short8;
typedef __attribute__((ext_vector_type(4))) float floatx4;

#define NW_ELEMS 589824        // 3*3*256*256
#define K_TOTAL 2304
#define PR_OFF 0
#define QV_OFF 2560
#define QC_OFF 5120
#define WQT_OFF 8192
#define XPAD_OFF 1187840
#define RED_BLOCKS 288         // 288*256*8 == NW_ELEMS exactly
#define PAD_BLOCKS 13456       // 32*58*58*256/8 / 256 (FULL coverage)

__device__ __forceinline__ void async16(const void* g, void* l) {
  __builtin_amdgcn_global_load_lds(
      (const __attribute__((address_space(1))) void*)g,
      (__attribute__((address_space(3))) void*)l, 16, 0, 0);
}

__device__ __forceinline__ ushort f2bf(float f) {
  __hip_bfloat16 h = __float2bfloat16(f);
  return *reinterpret_cast<ushort*>(&h);
}

// ---- fused: blocks 0..287 sum|W| -> pr[bid]; blocks 288.. pad x -> xpad ----
__global__ __launch_bounds__(256) void pad_sumabs_kernel(
    const float* __restrict__ x, ushort* __restrict__ xpad,
    const float* __restrict__ W, double* __restrict__ pr) {
  if (blockIdx.x < RED_BLOCKS) {
    __shared__ double sds[4];
    double v = 0.0;
#pragma unroll
    for (int j = 0; j < 8; j++) {
      uint i = (blockIdx.x * 8 + j) * 256 + threadIdx.x;
      v += (double)fabsf(W[i]);
    }
#pragma unroll
    for (int off = 32; off; off >>= 1) v += __shfl_down(v, off);
    if ((threadIdx.x & 63) == 0) sds[threadIdx.x >> 6] = v;
    __syncthreads();
    if (threadIdx.x == 0) pr[blockIdx.x] = sds[0] + sds[1] + sds[2] + sds[3];
    return;
  }
  uint idx = (blockIdx.x - RED_BLOCKS) * 256 + threadIdx.x;  // 1 thread / 8 ch
  uint c8 = idx & 31;
  uint sp = idx >> 5;                          // n*3364 + hh*58 + ww
  uint ww = sp % 58;
  uint t = sp / 58;
  uint hh = t % 58;
  uint n = t / 58;
  ushort* dst = xpad + ((size_t)sp * 256 + c8 * 8);
  if (hh == 0 || hh == 57 || ww == 0 || ww == 57) {
    uint4 z = {0, 0, 0, 0};
    *(uint4*)dst = z;
  } else {
    const float* src = x + (((size_t)(n * 56 + (hh - 1)) * 56 + (ww - 1)) * 256 + c8 * 8);
    float4 f0 = *(const float4*)src;
    float4 f1 = *(const float4*)(src + 4);
    ushort u[8];
    u[0] = f2bf(f0.x); u[1] = f2bf(f0.y); u[2] = f2bf(f0.z); u[3] = f2bf(f0.w);
    u[4] = f2bf(f1.x); u[5] = f2bf(f1.y); u[6] = f2bf(f1.z); u[7] = f2bf(f1.w);
    *(uint4*)dst = *(uint4*)u;
  }
}

// ---- ternarize: WqT[co][k] in {-1,0,+1}; per-block alpha-stat partials ----
__global__ __launch_bounds__(256) void quant_kernel(
    const float* __restrict__ W, ushort* __restrict__ WqT,
    const double* __restrict__ pr, double* __restrict__ qv,
    unsigned long long* __restrict__ qc) {
  __shared__ double sds[4];
  __shared__ unsigned long long cds[4];
  // global sum|W| from the 288 partials (L2-hot, plain loads, no atomics)
  double p = pr[threadIdx.x];
  if (threadIdx.x < 32) p += pr[256 + threadIdx.x];
#pragma unroll
  for (int off = 32; off; off >>= 1) p += __shfl_down(p, off);
  if ((threadIdx.x & 63) == 0) sds[threadIdx.x >> 6] = p;
  __syncthreads();
  double s = sds[0] + sds[1] + sds[2] + sds[3];
  float t = (float)(0.7 * (s / (double)NW_ELEMS));
  __syncthreads();  // sds reused below

  double v = 0.0;
  unsigned long long cnt = 0;
  ushort u[8];
#pragma unroll
  for (int j = 0; j < 8; j++) {
    uint i = (blockIdx.x * 8 + j) * 256 + threadIdx.x;
    float w = W[i];
    bool pos = (w > t), neg = (w < -t);
    u[j] = pos ? (ushort)0x3F80 : (neg ? (ushort)0xBF80 : (ushort)0);
    if (pos || neg) { v += (double)fabsf(w); cnt++; }
  }
  // thread (bid,tid) owns WqT[co=tid][k = bid*8 .. bid*8+7]: one 16B store
  *(uint4*)(WqT + (size_t)threadIdx.x * K_TOTAL + blockIdx.x * 8) = *(uint4*)u;
#pragma unroll
  for (int off = 32; off; off >>= 1) {
    v += __shfl_down(v, off);
    cnt += __shfl_down(cnt, off);
  }
  if ((threadIdx.x & 63) == 0) { sds[threadIdx.x >> 6] = v; cds[threadIdx.x >> 6] = cnt; }
  __syncthreads();
  if (threadIdx.x == 0) {
    qv[blockIdx.x] = sds[0] + sds[1] + sds[2] + sds[3];
    qc[blockIdx.x] = cds[0] + cds[1] + cds[2] + cds[3];
  }
}

// ---- implicit-GEMM conv: 128x128 tile, BK=64, 16x16x32 bf16 MFMA ----
// (R2 structure, verified 123us / 42% MfmaUtil / 0 bank conflicts.)
// LDS rows: 64 ushort = 128 B = 32 banks. Chunk c of row r stored at chunk
// slot c (staging loads global chunk c^(r&7)), readers fetch slot
// (kk*4+fq)^(fr&7): every bank gets exactly 8 dword accesses per b128 wave
// read -> conflict-free.
__global__ __launch_bounds__(256, 2) void conv_kernel(
    const ushort* __restrict__ xpad, const ushort* __restrict__ WqT,
    const double* __restrict__ qv, const unsigned long long* __restrict__ qc,
    const float* __restrict__ bias, float* __restrict__ out) {
  __shared__ __attribute__((aligned(16))) ushort Alds[128 * 64];  // 16 KB
  __shared__ __attribute__((aligned(16))) ushort Blds[128 * 64];  // 16 KB
  __shared__ double ads[4];
  __shared__ double acs[4];
  uint tid = threadIdx.x;
  uint bm = blockIdx.x >> 1, bn = blockIdx.x & 1;

  // staging: thread (rbase,chunk) loads global chunk ceff = chunk^(rbase&7)
  uint chunk = tid & 7;
  uint rbase = tid >> 3;       // 0..31
  uint ceff = chunk ^ (rbase & 7);
  const ushort* asrc[4];
  const ushort* bsrc[4];
#pragma unroll
  for (int i = 0; i < 4; i++) {
    uint row = i * 32 + rbase;
    uint gm = bm * 128 + row;
    uint n = gm / 3136;
    uint rem = gm - n * 3136;
    uint h = rem / 56;
    uint w = rem - h * 56;
    asrc[i] = xpad + (((size_t)(n * 58 + h) * 58 + w) * 256 + ceff * 8);
    bsrc[i] = WqT + ((size_t)(bn * 128 + row) * K_TOTAL + ceff * 8);
  }

  floatx4 acc[4][4];
#pragma unroll
  for (int mt = 0; mt < 4; mt++)
#pragma unroll
    for (int nt = 0; nt < 4; nt++) acc[mt][nt] = (floatx4){0.f, 0.f, 0.f, 0.f};

  uint lane = tid & 63;
  uint wv = tid >> 6;
  uint wm = wv >> 1, wn = wv & 1;   // 2x2 wave grid, each 64x64
  uint fr = lane & 15, fq = lane >> 4;
  uint a_row = (wm * 64 + fr) * 128;  // + mt*2048 + swz-chunk*16 (bytes)
  uint b_row = (wn * 64 + fr) * 128;
  uint swz = (fr & 7) * 16;           // XOR byte offset applied to chunk slot

  // K-loop: kc-outer, tap-inner (taps 1 step apart -> A re-reads L2-hot)
  for (int ks = 0; ks < 36; ks++) {
    uint kcq = (uint)ks / 9;
    uint tap = (uint)ks - kcq * 9;
    uint ky = tap / 3;
    uint kx = tap - ky * 3;
    uint aoffe = (ky * 58 + kx) * 256 + kcq * 64;  // elements into xpad
    uint boffe = tap * 256 + kcq * 64;             // elements along WqT row

    __syncthreads();  // previous tile fully consumed
#pragma unroll
    for (int i = 0; i < 4; i++)
      async16(asrc[i] + aoffe, (char*)Alds + i * 4096 + tid * 16);
#pragma unroll
    for (int i = 0; i < 4; i++)
      async16(bsrc[i] + boffe, (char*)Blds + i * 4096 + tid * 16);
    __syncthreads();  // drains vmcnt -> staging complete

#pragma unroll
    for (int kk = 0; kk < 2; kk++) {
      uint csl = ((uint)(kk * 64) + fq * 16) ^ swz;  // swizzled chunk slot
      short8 af[4], bfr[4];
#pragma unroll
      for (int mt = 0; mt < 4; mt++)
        af[mt] = *(const short8*)((const char*)Alds + a_row + mt * 2048 + csl);
#pragma unroll
      for (int nt = 0; nt < 4; nt++)
        bfr[nt] = *(const short8*)((const char*)Blds + b_row + nt * 2048 + csl);
#pragma unroll
      for (int mt = 0; mt < 4; mt++)
#pragma unroll
        for (int nt = 0; nt < 4; nt++)
          acc[mt][nt] = __builtin_amdgcn_mfma_f32_16x16x32_bf16(
              af[mt], bfr[nt], acc[mt][nt], 0, 0, 0);
    }
  }

  // alpha = sum(qv)/sum(qc) from 288 partials (L2-hot; block-redundant)
  double av = qv[tid];
  double ac = (double)qc[tid];
  if (tid < 32) { av += qv[256 + tid]; ac += (double)qc[256 + tid]; }
#pragma unroll
  for (int off = 32; off; off >>= 1) {
    av += __shfl_down(av, off);
    ac += __shfl_down(ac, off);
  }
  if ((tid & 63) == 0) { ads[tid >> 6] = av; acs[tid >> 6] = ac; }
  __syncthreads();
  float alpha = (float)((ads[0] + ads[1] + ads[2] + ads[3]) /
                        (acs[0] + acs[1] + acs[2] + acs[3]));

  // epilogue: alpha * acc + bias, fp32 store
  // C/D layout (m89/m91): col = lane&15, row = (lane>>4)*4 + reg
#pragma unroll
  for (int mt = 0; mt < 4; mt++) {
    uint mb = bm * 128 + wm * 64 + mt * 16 + fq * 4;
#pragma unroll
    for (int r = 0; r < 4; r++) {
      float* orow = out + (size_t)(mb + r) * 256;
#pragma unroll
      for (int nt = 0; nt < 4; nt++) {
        uint n = bn * 128 + wn * 64 + nt * 16 + fr;
        orow[n] = acc[mt][nt][r] * alpha + bias[n];
      }
    }
  }
}

extern "C" void kernel_launch(void* const* d_in, const int* in_sizes, int n_in,
                              void* d_out, int out_size, void* d_ws, size_t ws_size,
                              hipStream_t stream) {
  const float* x = (const float*)d_in[0];
  const float* W = (const float*)d_in[1];
  const float* b = (const float*)d_in[2];
  float* out = (float*)d_out;

  double* pr = (double*)((char*)d_ws + PR_OFF);
  double* qv = (double*)((char*)d_ws + QV_OFF);
  unsigned long long* qc = (unsigned long long*)((char*)d_ws + QC_OFF);
  ushort* WqT = (ushort*)((char*)d_ws + WQT_OFF);
  ushort* xpad = (ushort*)((char*)d_ws + XPAD_OFF);

  pad_sumabs_kernel<<<RED_BLOCKS + PAD_BLOCKS, 256, 0, stream>>>(x, xpad, W, pr);
  quant_kernel<<<RED_BLOCKS, 256, 0, stream>>>(W, WqT, pr, qv, qc);
  conv_kernel<<<1568, 256, 0, stream>>>(xpad, WqT, qv, qc, b, out);
}